// Round 19
// baseline (48.129 us; speedup 1.0000x reference)
//
#include <hip/hip_runtime.h>
#include <stdint.h>

typedef _Float16 f16x8 __attribute__((ext_vector_type(8)));
typedef __fp16 fp16x2 __attribute__((ext_vector_type(2)));
typedef float f32x4 __attribute__((ext_vector_type(4)));

#define BC (16384 * 256)

__device__ __forceinline__ f16x8 cvt8(f32x4 a, f32x4 b) {
  fp16x2 p0 = __builtin_amdgcn_cvt_pkrtz(a[0], a[1]);
  fp16x2 p1 = __builtin_amdgcn_cvt_pkrtz(a[2], a[3]);
  fp16x2 p2 = __builtin_amdgcn_cvt_pkrtz(b[0], b[1]);
  fp16x2 p3 = __builtin_amdgcn_cvt_pkrtz(b[2], b[3]);
  f16x8 o;
  o[0] = (_Float16)p0[0]; o[1] = (_Float16)p0[1];
  o[2] = (_Float16)p1[0]; o[3] = (_Float16)p1[1];
  o[4] = (_Float16)p2[0]; o[5] = (_Float16)p2[1];
  o[6] = (_Float16)p3[0]; o[7] = (_Float16)p3[1];
  return o;
}

__device__ __forceinline__ float tanh_fast(float v) {
  float a = fminf(fabsf(v), 18.f);
  float t = __expf(2.f * a);
  float r = (t - 1.f) * __builtin_amdgcn_rcpf(t + 1.f);
  return copysignf(r, v);
}

// Pack Wu/Wg/Wa/Wd -> wsB f16, kt-outermost, BK=32 LDS swizzle baked in
// (R14 layout, verified):
// elem = (((kt*8 + cb)*128 + row)*4 + slot)*8 + b, holding W_strip[c][k] with
//   row = wn*64 + strip*16 + t16, c = cb*32 + wn*16 + t16,
//   k = kt*32 + (slot ^ ((row>>1)&3))*8 + b.
// strip 0 = Wu (k >= 256 zero-padded).
__global__ __launch_bounds__(256) void pack_w(const float* __restrict__ Wu,
                                              const float* __restrict__ Wg,
                                              const float* __restrict__ Wa,
                                              const float* __restrict__ Wd,
                                              _Float16* __restrict__ wsB) {
  int tid = blockIdx.x * 256 + threadIdx.x;  // 65536 total
  int slot = tid & 3;
  int row = (tid >> 2) & 127;
  int cb = (tid >> 9) & 7;
  int kt = tid >> 12;  // 0..15
  int strip = (row >> 4) & 3;
  int wn = row >> 6;
  int t16 = row & 15;
  int c = cb * 32 + wn * 16 + t16;
  int k0 = kt * 32 + (slot ^ ((row >> 1) & 3)) * 8;
  float v[8];
  if (strip == 0) {
    if (k0 < 256) {
      const float* p = Wu + (size_t)c * 256 + k0;
#pragma unroll
      for (int i = 0; i < 8; ++i) v[i] = p[i];
    } else {
#pragma unroll
      for (int i = 0; i < 8; ++i) v[i] = 0.f;
    }
  } else {
    const float* p = (strip == 1 ? Wg : (strip == 2 ? Wa : Wd)) + (size_t)c * 512 + k0;
#pragma unroll
    for (int i = 0; i < 8; ++i) v[i] = p[i];
  }
  f32x4 a = {v[0], v[1], v[2], v[3]};
  f32x4 b = {v[4], v[5], v[6], v[7]};
  *reinterpret_cast<f16x8*>(wsB + (size_t)tid * 8) = cvt8(a, b);
}

// R14 schedule, bigger tile: block 128 rows x 128 packed cols, 4 waves
// (2M x 2N), wave tile 64x64, BK=32, dbuf LDS 32 KB. Grid 1024 = exactly
// 4 blocks/CU, all resident, zero tail. Per iter: issue A-gloads(kt+1) [4] +
// B-glds(kt+1) [2]; vmcnt(6) retires B(kt) only; barrier; 16 MFMA (mi-outer);
// writeA (implicit vmcnt(2)); lgkmcnt(0); barrier.
__global__ __launch_bounds__(256, 4) void rwa_main(
    const float* __restrict__ x, const float* __restrict__ nt_,
    const float* __restrict__ dt_, const float* __restrict__ h,
    const float* __restrict__ amax_, const float* __restrict__ bu,
    const float* __restrict__ bg, const _Float16* __restrict__ wsB,
    float* __restrict__ out) {
  __shared__ __align__(16) _Float16 ldsA[2][128 * 32];  // 2 x 8 KB
  __shared__ __align__(16) _Float16 ldsB[2][128 * 32];  // 2 x 8 KB

  const int tid = threadIdx.x;
  const int lane = tid & 63;
  const int l15 = lane & 15;
  const int lg = lane >> 4;
  const int wv = tid >> 6;
  const int wm = wv & 1;   // wave row-half (64 rows)
  const int wn = wv >> 1;  // wave packed-col half (64)

  // XCD swizzle: 8 cb-blocks of one rowblk share an XCD -> A panel + weights L2-hot.
  const int bid = blockIdx.x;  // 0..1023
  const int xcd = bid & 7;
  const int q = bid >> 3;      // 0..127
  const int cb = q & 7;
  const int rowblk = xcd * 16 + (q >> 3);  // 0..127
  const int row0 = rowblk * 128;

  // A staging: thread stages row ar (0..127), 16-float half aq (0..1).
  const int ar = tid >> 1;
  const int aq = tid & 1;

  // B staging source (R14 layout): per (kt,cb) slab 8 KB; thread t copies 16 B x 2.
  const _Float16* bsrc0 = wsB + (size_t)cb * 4096 + (size_t)tid * 8;

  f32x4 acc[4][4] = {};   // [mi][strip]
  f32x4 av[4];            // in-flight A staging regs (next tile, 16 floats)

  auto issueA = [&](int kt) {
    const float* sp = (kt < 8 ? x : h) + (size_t)(row0 + ar) * 256 + (kt & 7) * 32 + aq * 16;
#pragma unroll
    for (int i = 0; i < 4; ++i) av[i] = *reinterpret_cast<const f32x4*>(sp + i * 4);
  };
  auto issueB = [&](int buf, int kt) {
#pragma unroll
    for (int i = 0; i < 2; ++i) {
      __builtin_amdgcn_global_load_lds(
          (const __attribute__((address_space(1))) uint32_t*)(bsrc0 + (size_t)kt * 32768 + i * 2048),
          (__attribute__((address_space(3))) uint32_t*)(&ldsB[buf][0] + wv * 512 + i * 2048),
          16, 0, 0);
    }
  };
  auto writeA = [&](int buf) {
    char* base = reinterpret_cast<char*>(&ldsA[buf][0]) + ar * 64;
#pragma unroll
    for (int j = 0; j < 2; ++j) {
      f16x8 o = cvt8(av[2 * j], av[2 * j + 1]);
      const int slot = (aq * 2 + j) ^ ((ar >> 1) & 3);
      *reinterpret_cast<f16x8*>(base + slot * 16) = o;
    }
  };

  // Prologue: tile 0 into buf 0. B(0) glds stay pending until first B1.
  issueA(0);
  issueB(0, 0);
  writeA(0);  // compiler inserts vmcnt for av only; B(0) keeps flying

#pragma unroll
  for (int kt = 0; kt < 16; ++kt) {
    const int buf = kt & 1;
    if (kt < 15) {
      issueA(kt + 1);       // 4 gloads
      issueB(buf ^ 1, kt + 1);  // 2 glds
    }

    // B1: retire B(kt); the 6 newest (A+B of kt+1) stay in flight.
    if (kt < 15) {
      asm volatile("s_waitcnt vmcnt(6) lgkmcnt(0)" ::: "memory");
    } else {
      asm volatile("s_waitcnt vmcnt(0) lgkmcnt(0)" ::: "memory");
    }
    __builtin_amdgcn_s_barrier();
    __builtin_amdgcn_sched_barrier(0);

    // Compute tile kt: 16 MFMA (12 when Wu strip skipped), mi-outer.
    const bool doU = (kt < 8);  // Wu strip zero-padded beyond k=256
    const char* pA = reinterpret_cast<const char*>(&ldsA[buf][0]);
    const char* pB = reinterpret_cast<const char*>(&ldsB[buf][0]);
    {
      f16x8 bf[4];
#pragma unroll
      for (int s = 0; s < 4; ++s) {
        if (s == 0 && !doU) continue;
        const int pc = wn * 64 + s * 16 + l15;
        bf[s] = *reinterpret_cast<const f16x8*>(pB + pc * 64 + ((lg ^ ((pc >> 1) & 3)) << 4));
      }
#pragma unroll
      for (int mi = 0; mi < 4; ++mi) {
        const int row = wm * 64 + mi * 16 + l15;
        f16x8 af = *reinterpret_cast<const f16x8*>(pA + row * 64 + ((lg ^ ((row >> 1) & 3)) << 4));
#pragma unroll
        for (int s = 0; s < 4; ++s) {
          if (s == 0 && !doU) continue;
          acc[mi][s] = __builtin_amdgcn_mfma_f32_16x16x32_f16(af, bf[s], acc[mi][s], 0, 0, 0);
        }
      }
    }

    if (kt < 15) {
      writeA(buf ^ 1);  // implicit vmcnt(2): waits A(kt+1) gloads only
      asm volatile("s_waitcnt lgkmcnt(0)" ::: "memory");
      __builtin_amdgcn_s_barrier();
      __builtin_amdgcn_sched_barrier(0);
    }
  }

  __builtin_amdgcn_sched_barrier(0);  // keep epilogue loads below the loop

  // Epilogue: lane owns (r,c); u,g,a,dec local.
  const int c = cb * 32 + wn * 16 + l15;
  const float buv = bu[c];
  const float bgv = bg[c];
#pragma unroll
  for (int mi = 0; mi < 4; ++mi) {
#pragma unroll
    for (int rg = 0; rg < 4; ++rg) {
      const int r = row0 + wm * 64 + mi * 16 + lg * 4 + rg;
      const int idx = r * 256 + c;
      const float u = acc[mi][0][rg] + buv;
      const float gt = acc[mi][1][rg] + bgv;
      const float a = acc[mi][2][rg];
      const float dr = acc[mi][3][rg];
      const float sig = __builtin_amdgcn_rcpf(1.f + __expf(-dr));
      const float z = u * tanh_fast(gt);
      const float am = amax_[idx];
      const float n_old = nt_[idx];
      const float d_old = dt_[idx];
      const float e_neg = __expf(-sig);
      const float a_new = fmaxf(am * e_neg, a);
      const float comm = __expf(am - a_new - sig);  // e_neg * exp(am - a_new)
      const float escal = __expf(a - a_new);
      const float n_new = n_old * comm + z * escal;
      const float d_new = d_old * comm + escal;
      const float h_new = tanh_fast(n_new * __builtin_amdgcn_rcpf(d_new));
      out[idx] = n_new;
      out[BC + idx] = d_new;
      out[2 * BC + idx] = h_new;
      out[3 * BC + idx] = a_new;
    }
  }
}

extern "C" void kernel_launch(void* const* d_in, const int* in_sizes, int n_in,
                              void* d_out, int out_size, void* d_ws, size_t ws_size,
                              hipStream_t stream) {
  const float* x_t    = (const float*)d_in[0];
  const float* n_t    = (const float*)d_in[1];
  const float* d_t    = (const float*)d_in[2];
  const float* h_t    = (const float*)d_in[3];
  const float* amax_t = (const float*)d_in[4];
  const float* Wu     = (const float*)d_in[5];
  const float* bu     = (const float*)d_in[6];
  const float* Wg     = (const float*)d_in[7];
  const float* bg     = (const float*)d_in[8];
  const float* Wa     = (const float*)d_in[9];
  const float* Wd     = (const float*)d_in[10];
  float* out = (float*)d_out;

  _Float16* wsB = (_Float16*)d_ws;  // 1 MB packed weights (kt-outermost, BK=32)

  pack_w<<<256, 256, 0, stream>>>(Wu, Wg, Wa, Wd, wsB);
  rwa_main<<<1024, 256, 0, stream>>>(x_t, n_t, d_t, h_t, amax_t, bu, bg, wsB, out);
}